// Round 9
// baseline (511.766 us; speedup 1.0000x reference)
//
#include <hip/hip_runtime.h>

#define N_NODES 50000
#define N_EDGES 800000
#define DIN 384
#define DH 128
#define NB 64
#define NEG 0.2f

// ---------------- bf16 helpers (exact bit ops) ----------------
__device__ __forceinline__ float bf2f(unsigned short u) {
    return __uint_as_float((unsigned)u << 16);
}
__device__ __forceinline__ unsigned short f2bf(float x) {  // RNE
    unsigned u = __float_as_uint(x);
    return (unsigned short)((u + 0x7fff + ((u >> 16) & 1)) >> 16);
}
using us8 = __attribute__((ext_vector_type(8))) unsigned short;

// ---------------- fused histogram + edge-weight sum ----------------
__global__ __launch_bounds__(256) void histew_kernel(const int* __restrict__ dst,
                                                     const float* __restrict__ ew,
                                                     int* __restrict__ cnt,
                                                     float* __restrict__ ews) {
    __shared__ float sred[4];
    const int tid = threadIdx.x;
    float v = 0.0f;
    for (int i = blockIdx.x * 256 + tid; i < N_EDGES; i += gridDim.x * 256) {
        atomicAdd(&cnt[dst[i]], 1);
        v += ew[i];
    }
    #pragma unroll
    for (int o = 32; o; o >>= 1) v += __shfl_down(v, o, 64);
    if ((tid & 63) == 0) sred[tid >> 6] = v;
    __syncthreads();
    if (tid == 0) atomicAdd(ews, sred[0] + sred[1] + sred[2] + sred[3]);
}

// ---------------- single-dispatch exclusive scan (1 block, 1024 thr) ----------
__global__ __launch_bounds__(1024) void scan_kernel(const int* __restrict__ cnt,
                                                    int* __restrict__ ptr,
                                                    int* __restrict__ cursor) {
    __shared__ int ws[16];
    const int tid = threadIdx.x;
    const int wid = tid >> 6, lane = tid & 63;
    int running = 0;
    for (int base = 0; base < N_NODES; base += 1024) {
        const int i = base + tid;
        const int v = (i < N_NODES) ? cnt[i] : 0;
        int incl = v;
        #pragma unroll
        for (int o = 1; o < 64; o <<= 1) {
            int t = __shfl_up(incl, o, 64);
            if (lane >= o) incl += t;
        }
        if (lane == 63) ws[wid] = incl;
        __syncthreads();
        if (tid < 64) {
            int x = (tid < 16) ? ws[tid] : 0;
            #pragma unroll
            for (int o = 1; o < 16; o <<= 1) {
                int t = __shfl_up(x, o, 64);
                if (tid >= o) x += t;
            }
            if (tid < 16) ws[tid] = x;   // inclusive scan of wave sums
        }
        __syncthreads();
        const int wpre = wid ? ws[wid - 1] : 0;
        const int excl = running + wpre + incl - v;
        if (i < N_NODES) { ptr[i] = excl; cursor[i] = excl; }
        running += ws[15];
        __syncthreads();
    }
    if (tid == 0) ptr[N_NODES] = running;
}

// fill: one 16 B record {src, dst, ew} per edge into dst-sorted order.
// (One scattered store, not three — line-allocate traffic ~3x lower.)
__global__ void fill_kernel(const int* __restrict__ src, const int* __restrict__ dst,
                            const float* __restrict__ ew, int* __restrict__ cursor,
                            int4* __restrict__ recQ) {
    int e = blockIdx.x * blockDim.x + threadIdx.x;
    if (e < N_EDGES) {
        int d = dst[e];
        int p = atomicAdd(&cursor[d], 1);
        int4 r = {src[e], d, __float_as_int(ew[e]), 0};
        recQ[p] = r;
    }
}

// ---------------- MFMA bf16 GEMM: C[M,128] = A[M,K] @ W[K,128] (+bias) ----------
// BF16OUT variant also computes per-row attention logits asrc/adst from the fp32
// accumulator (replaces a separate att kernel + h re-read).
template<int K, bool BF16OUT>
__global__ __launch_bounds__(256) void mfma_gemm(const float* __restrict__ A,
                                                 const float* __restrict__ W,
                                                 const float* __restrict__ bias,
                                                 void* __restrict__ Cv, int M,
                                                 const float* __restrict__ a_s,
                                                 const float* __restrict__ a_d,
                                                 float* __restrict__ asrc_o,
                                                 float* __restrict__ adst_o)
{
    constexpr int BM = 64, BK = 32;
    constexpr int LS = 40;   // LDS row stride in bf16 (80 B: conflict-spreading pad)
    __shared__ unsigned short As[BM * LS];   // [m][k]
    __shared__ unsigned short Bs[DH * LS];   // [n][k]  (W transposed)
    using short8 = __attribute__((ext_vector_type(8))) short;
    using f32x4  = __attribute__((ext_vector_type(4))) float;

    const int tid = threadIdx.x;
    const int w = tid >> 6, l = tid & 63;
    const int lane16 = l & 15, quad = l >> 4;
    const int m0 = blockIdx.x * BM;

    f32x4 acc[8] = {};

    const int ar = tid >> 2, af = tid & 3;
    int arow = m0 + ar; if (arow >= M) arow = M - 1;
    const float* Ap = A + (size_t)arow * K;
    const int bn = tid & 127, bq = tid >> 7;

    for (int k0 = 0; k0 < K; k0 += BK) {
        __syncthreads();
        #pragma unroll
        for (int i = 0; i < 2; ++i) {
            const int f4 = af + 4 * i;
            float4 v = *(const float4*)(Ap + k0 + f4 * 4);
            ushort4 u = {f2bf(v.x), f2bf(v.y), f2bf(v.z), f2bf(v.w)};
            *(ushort4*)&As[ar * LS + f4 * 4] = u;
        }
        #pragma unroll
        for (int i = 0; i < 4; ++i) {
            const int kq = bq + 2 * i;   // 0..7
            float v0 = W[(size_t)(k0 + kq * 4 + 0) * DH + bn];
            float v1 = W[(size_t)(k0 + kq * 4 + 1) * DH + bn];
            float v2 = W[(size_t)(k0 + kq * 4 + 2) * DH + bn];
            float v3 = W[(size_t)(k0 + kq * 4 + 3) * DH + bn];
            ushort4 u = {f2bf(v0), f2bf(v1), f2bf(v2), f2bf(v3)};
            *(ushort4*)&Bs[bn * LS + kq * 4] = u;
        }
        __syncthreads();
        short8 afrag = *(short8*)&As[(w * 16 + lane16) * LS + quad * 8];
        #pragma unroll
        for (int nt = 0; nt < 8; ++nt) {
            short8 bfrag = *(short8*)&Bs[(nt * 16 + lane16) * LS + quad * 8];
            acc[nt] = __builtin_amdgcn_mfma_f32_16x16x32_bf16(afrag, bfrag, acc[nt], 0, 0, 0);
        }
    }

    const int orow0 = m0 + w * 16 + quad * 4;
    #pragma unroll
    for (int nt = 0; nt < 8; ++nt) {
        const int col = nt * 16 + lane16;
        const float bv = BF16OUT ? 0.0f : bias[col];
        #pragma unroll
        for (int r = 0; r < 4; ++r) {
            const int row = orow0 + r;
            if (row < M) {
                if constexpr (BF16OUT)
                    ((unsigned short*)Cv)[(size_t)row * DH + col] = f2bf(acc[nt][r]);
                else
                    ((float*)Cv)[(size_t)row * DH + col] = acc[nt][r] + bv;
            }
        }
    }

    if constexpr (BF16OUT) {
        // attention logits: asrc[row][hd] = sum_{f in head} h[row][hd*32+f]*a_s[hd][f]
        float psh[4][4] = {}, pdh[4][4] = {};   // [head][r]
        #pragma unroll
        for (int nt = 0; nt < 8; ++nt) {
            const int hd = nt >> 1;
            const float asv = a_s[nt * 16 + lane16];
            const float adv = a_d[nt * 16 + lane16];
            #pragma unroll
            for (int r = 0; r < 4; ++r) {
                psh[hd][r] = fmaf(acc[nt][r], asv, psh[hd][r]);
                pdh[hd][r] = fmaf(acc[nt][r], adv, pdh[hd][r]);
            }
        }
        #pragma unroll
        for (int o = 1; o < 16; o <<= 1) {
            #pragma unroll
            for (int hd = 0; hd < 4; ++hd)
                #pragma unroll
                for (int r = 0; r < 4; ++r) {
                    psh[hd][r] += __shfl_xor(psh[hd][r], o, 64);
                    pdh[hd][r] += __shfl_xor(pdh[hd][r], o, 64);
                }
        }
        if (lane16 == 0) {
            #pragma unroll
            for (int r = 0; r < 4; ++r) {
                const int row = orow0 + r;
                if (row < M) {
                    float4 o1 = {psh[0][r], psh[1][r], psh[2][r], psh[3][r]};
                    float4 o2 = {pdh[0][r], pdh[1][r], pdh[2][r], pdh[3][r]};
                    *(float4*)(asrc_o + (size_t)row * 4) = o1;
                    *(float4*)(adst_o + (size_t)row * 4) = o2;
                }
            }
        }
    }
}

// ---------------- edge-parallel alpha from records ----------------
// Reads 16 B records coalesced; emits alQ (float4) + srcQ (dense int) sequentially.
__global__ __launch_bounds__(256) void alpha_kernel(
    const int4* __restrict__ recQ, const float* __restrict__ asrc,
    const float* __restrict__ adst, const float* __restrict__ Wedge,
    const float* __restrict__ aedge, float* __restrict__ alQ,
    int* __restrict__ srcQ)
{
    const int l = threadIdx.x & 63;
    float p0 = Wedge[l] * aedge[l];
    float p1 = Wedge[l + 64] * aedge[l + 64];
    #pragma unroll
    for (int o = 1; o < 32; o <<= 1) { p0 += __shfl_xor(p0, o, 64); p1 += __shfl_xor(p1, o, 64); }
    const float cc0 = __shfl(p0, 0, 64), cc1 = __shfl(p0, 32, 64);
    const float cc2 = __shfl(p1, 0, 64), cc3 = __shfl(p1, 32, 64);

    const int e = blockIdx.x * 256 + threadIdx.x;
    if (e >= N_EDGES) return;
    const int4 r = recQ[e];
    const int s = r.x, d = r.y;
    const float wgt = __int_as_float(r.z);
    srcQ[e] = s;
    const float4 a4 = *(const float4*)(asrc + (size_t)s * 4);
    const float4 b4 = *(const float4*)(adst + (size_t)d * 4);
    float v0 = a4.x + b4.x + wgt * cc0;
    float v1 = a4.y + b4.y + wgt * cc1;
    float v2 = a4.z + b4.z + wgt * cc2;
    float v3 = a4.w + b4.w + wgt * cc3;
    v0 = v0 > 0.f ? v0 : NEG * v0;
    v1 = v1 > 0.f ? v1 : NEG * v1;
    v2 = v2 > 0.f ? v2 : NEG * v2;
    v3 = v3 > 0.f ? v3 : NEG * v3;
    // |alpha| << 1 -> exp without max-shift is exact softmax (shift-invariant)
    float4 o4 = {__expf(v0), __expf(v1), __expf(v2), __expf(v3)};
    *(float4*)(alQ + (size_t)e * 4) = o4;
}

// ---------------- msg: pure gather, LDS-free, 4 nodes / 256-thr block ----------
#define MSG_NPB 4
__global__ __launch_bounds__(256) void msg_kernel(
    const unsigned short* __restrict__ h, const float* __restrict__ asrc,
    const float* __restrict__ adst, const float* __restrict__ xres,
    const int* __restrict__ indptr, const int* __restrict__ srcQ,
    const float* __restrict__ alQ, const float* __restrict__ ewsum,
    const float* __restrict__ Wedge, const float* __restrict__ aedge,
    const float* __restrict__ bias, const float* __restrict__ gamma,
    const float* __restrict__ beta, float* __restrict__ xout)
{
    const int l = threadIdx.x & 63;
    const int n = blockIdx.x * MSG_NPB + (threadIdx.x >> 6);
    if (n >= N_NODES) return;
    const int sub2 = l >> 4, c8 = l & 15, hd8 = c8 >> 2;

    // c[k] = dot(We_k, ae_k) for self-loop logit
    float p0 = Wedge[l] * aedge[l];
    float p1 = Wedge[l + 64] * aedge[l + 64];
    #pragma unroll
    for (int o = 1; o < 32; o <<= 1) { p0 += __shfl_xor(p0, o, 64); p1 += __shfl_xor(p1, o, 64); }
    float cc[4];
    cc[0] = __shfl(p0, 0, 64);  cc[1] = __shfl(p0, 32, 64);
    cc[2] = __shfl(p1, 0, 64);  cc[3] = __shfl(p1, 32, 64);

    const float4 ad4 = *(const float4*)(adst + (size_t)n * 4);
    const float4 as4 = *(const float4*)(asrc + (size_t)n * 4);
    const float ewm = ewsum[0] * (1.0f / N_EDGES);
    float pv0[4];
    {
        const float av[4] = {as4.x, as4.y, as4.z, as4.w};
        const float dv[4] = {ad4.x, ad4.y, ad4.z, ad4.w};
        #pragma unroll
        for (int k = 0; k < 4; ++k) {
            float a0 = av[k] + dv[k] + ewm * cc[k];
            a0 = a0 > 0.f ? a0 : NEG * a0;
            pv0[k] = __expf(a0);
        }
    }

    float dsum = 0.f;
    float acc8[8] = {};
    const unsigned short* hb = h + c8 * 8;
    if (sub2 == 0) {
        us8 u = *(const us8*)(hb + (size_t)n * DH);
        const float f = pv0[hd8];
        #pragma unroll
        for (int i = 0; i < 8; ++i) acc8[i] = f * bf2f(u[i]);
    }

    const int st = indptr[n], deg = indptr[n + 1] - st;
    const int* sq = srcQ + st;
    const float* aq = alQ + (size_t)st * 4 + hd8;
    int e = sub2;
    for (; e + 12 < deg; e += 16) {
        const int s0 = sq[e],     s1 = sq[e + 4];
        const int s2 = sq[e + 8], s3 = sq[e + 12];
        const float c0 = aq[(size_t)e * 4],        c1 = aq[(size_t)(e + 4) * 4];
        const float c2 = aq[(size_t)(e + 8) * 4],  c3 = aq[(size_t)(e + 12) * 4];
        us8 u0 = *(const us8*)(hb + (size_t)s0 * DH);
        us8 u1 = *(const us8*)(hb + (size_t)s1 * DH);
        us8 u2 = *(const us8*)(hb + (size_t)s2 * DH);
        us8 u3 = *(const us8*)(hb + (size_t)s3 * DH);
        dsum += c0 + c1 + c2 + c3;
        #pragma unroll
        for (int i = 0; i < 8; ++i)
            acc8[i] = fmaf(c0, bf2f(u0[i]),
                      fmaf(c1, bf2f(u1[i]),
                      fmaf(c2, bf2f(u2[i]),
                      fmaf(c3, bf2f(u3[i]), acc8[i]))));
    }
    for (; e < deg; e += 4) {
        const int s = sq[e];
        const float coef = aq[(size_t)e * 4];
        us8 u = *(const us8*)(hb + (size_t)s * DH);
        dsum += coef;
        #pragma unroll
        for (int i = 0; i < 8; ++i) acc8[i] = fmaf(coef, bf2f(u[i]), acc8[i]);
    }

    // reduce over the 4 edge-parity groups (bits 4,5 of lane id)
    #pragma unroll
    for (int i = 0; i < 8; ++i) {
        acc8[i] += __shfl_xor(acc8[i], 16, 64);
        acc8[i] += __shfl_xor(acc8[i], 32, 64);
    }
    dsum += __shfl_xor(dsum, 16, 64);
    dsum += __shfl_xor(dsum, 32, 64);

    const float inv_d = 1.0f / (dsum + pv0[hd8] + 1e-16f);
    const float4 b4a = *(const float4*)(bias + c8 * 8);
    const float4 b4b = *(const float4*)(bias + c8 * 8 + 4);
    float y[8];
    y[0] = acc8[0] * inv_d + b4a.x; y[1] = acc8[1] * inv_d + b4a.y;
    y[2] = acc8[2] * inv_d + b4a.z; y[3] = acc8[3] * inv_d + b4a.w;
    y[4] = acc8[4] * inv_d + b4b.x; y[5] = acc8[5] * inv_d + b4b.y;
    y[6] = acc8[6] * inv_d + b4b.z; y[7] = acc8[7] * inv_d + b4b.w;

    float s1 = 0.f, s2 = 0.f;
    #pragma unroll
    for (int i = 0; i < 8; ++i) { s1 += y[i]; s2 += y[i] * y[i]; }
    #pragma unroll
    for (int o = 1; o < 16; o <<= 1) {
        s1 += __shfl_xor(s1, o, 64);
        s2 += __shfl_xor(s2, o, 64);
    }
    const float mu = s1 * (1.0f / DH);
    const float var = s2 * (1.0f / DH) - mu * mu;
    const float rs = rsqrtf(var + 1e-5f);

    if (sub2 == 0) {
        const float4 g4a = *(const float4*)(gamma + c8 * 8);
        const float4 g4b = *(const float4*)(gamma + c8 * 8 + 4);
        const float4 e4a = *(const float4*)(beta + c8 * 8);
        const float4 e4b = *(const float4*)(beta + c8 * 8 + 4);
        const float4 r4a = *(const float4*)(xres + (size_t)n * DH + c8 * 8);
        const float4 r4b = *(const float4*)(xres + (size_t)n * DH + c8 * 8 + 4);
        const float gv[8] = {g4a.x, g4a.y, g4a.z, g4a.w, g4b.x, g4b.y, g4b.z, g4b.w};
        const float ev[8] = {e4a.x, e4a.y, e4a.z, e4a.w, e4b.x, e4b.y, e4b.z, e4b.w};
        const float rv[8] = {r4a.x, r4a.y, r4a.z, r4a.w, r4b.x, r4b.y, r4b.z, r4b.w};
        float z[8];
        #pragma unroll
        for (int i = 0; i < 8; ++i) {
            float t = (y[i] - mu) * rs * gv[i] + ev[i];
            z[i] = (t > 0.f ? t : __expf(t) - 1.0f) + rv[i];
        }
        *(float4*)(xout + (size_t)n * DH + c8 * 8)     = *(float4*)&z[0];
        *(float4*)(xout + (size_t)n * DH + c8 * 8 + 4) = *(float4*)&z[4];
    }
}

// ---------------- global mean pool ----------------
#define PNODES 64
__global__ __launch_bounds__(128) void pool_kernel(const float* __restrict__ x,
        const int* __restrict__ batch, float* __restrict__ pool, int* __restrict__ gcnt)
{
    int t = threadIdx.x;
    int n0 = blockIdx.x * PNODES;
    if (n0 >= N_NODES) return;
    int n1 = min(n0 + PNODES, N_NODES);
    float acc = 0.f; int cn = 0;
    int curb = batch[n0];
    for (int n = n0; n < n1; ++n) {
        int b = batch[n];
        if (b != curb) {
            atomicAdd(&pool[(size_t)curb * DH + t], acc);
            if (t == 0) atomicAdd(&gcnt[curb], cn);
            acc = 0.f; cn = 0; curb = b;
        }
        acc += x[(size_t)n * DH + t];
        ++cn;
    }
    atomicAdd(&pool[(size_t)curb * DH + t], acc);
    if (t == 0) atomicAdd(&gcnt[curb], cn);
}

__global__ void div_kernel(const float* __restrict__ pool, const int* __restrict__ gcnt,
                           float* __restrict__ out)
{
    int i = blockIdx.x * blockDim.x + threadIdx.x;
    if (i < NB * DH) {
        float c = (float)gcnt[i >> 7];
        out[i] = pool[i] / fmaxf(c, 1.0f);
    }
}

// ---------------- launch ----------------
extern "C" void kernel_launch(void* const* d_in, const int* in_sizes, int n_in,
                              void* d_out, int out_size, void* d_ws, size_t ws_size,
                              hipStream_t stream)
{
    const float* nf    = (const float*)d_in[0];
    const int*   esrc  = (const int*)d_in[1];
    const int*   edst  = esrc + N_EDGES;
    const float* ew    = (const float*)d_in[2];
    const int*   batch = (const int*)d_in[3];
    const float* Wp    = (const float*)d_in[4];
    const float* bp    = (const float*)d_in[5];
    const float* Wl[2]  = {(const float*)d_in[6],  (const float*)d_in[14]};
    const float* asl[2] = {(const float*)d_in[7],  (const float*)d_in[15]};
    const float* adl[2] = {(const float*)d_in[8],  (const float*)d_in[16]};
    const float* Wel[2] = {(const float*)d_in[9],  (const float*)d_in[17]};
    const float* ael[2] = {(const float*)d_in[10], (const float*)d_in[18]};
    const float* bl[2]  = {(const float*)d_in[11], (const float*)d_in[19]};
    const float* gl[2]  = {(const float*)d_in[12], (const float*)d_in[20]};
    const float* bel[2] = {(const float*)d_in[13], (const float*)d_in[21]};
    float* outp = (float*)d_out;

    char* w = (char*)d_ws;
    auto alloc = [&](size_t bytes) { char* p = w; w += (bytes + 255) & ~255ull; return p; };
    float* xA     = (float*)alloc((size_t)N_NODES * DH * 4);
    float* xB     = (float*)alloc((size_t)N_NODES * DH * 4);
    unsigned short* hbuf = (unsigned short*)alloc((size_t)N_NODES * DH * 2);
    float* asrc   = (float*)alloc((size_t)N_NODES * 4 * 4);
    float* adst   = (float*)alloc((size_t)N_NODES * 4 * 4);
    // contiguous zero-init group: pool | gcnt | ews | cnt  (one memset)
    float* pool   = (float*)alloc((size_t)NB * DH * 4);     // 32768 B
    int* gcnt     = (int*)alloc(256);
    float* ews    = (float*)alloc(256);
    int* cnt      = (int*)alloc((size_t)N_NODES * 4);
    int* ptr      = (int*)alloc((size_t)(N_NODES + 8) * 4);
    int* cursor   = (int*)alloc((size_t)N_NODES * 4);
    int* srcQ     = (int*)alloc((size_t)N_EDGES * 4);
    int4* recQ    = (int4*)alloc((size_t)N_EDGES * 16);
    float* alQ    = (float*)alloc((size_t)N_EDGES * 4 * 4);

    hipMemsetAsync(pool, 0, (size_t)NB * DH * 4 + 256 + 256 + (size_t)N_NODES * 4, stream);

    const int eb = (N_EDGES + 255) / 256;  // 3125

    histew_kernel<<<1024, 256, 0, stream>>>(edst, ew, cnt, ews);
    scan_kernel<<<1, 1024, 0, stream>>>(cnt, ptr, cursor);
    fill_kernel<<<eb, 256, 0, stream>>>(esrc, edst, ew, cursor, recQ);

    const int gb = (N_NODES + 63) / 64;  // 782
    mfma_gemm<DIN, false><<<gb, 256, 0, stream>>>(nf, Wp, bp, xA, N_NODES,
                                                  nullptr, nullptr, nullptr, nullptr);

    const float* xin = xA;
    float* xout = xB;
    for (int l = 0; l < 2; ++l) {
        mfma_gemm<DH, true><<<gb, 256, 0, stream>>>(xin, Wl[l], nullptr, hbuf, N_NODES,
                                                    asl[l], adl[l], asrc, adst);
        alpha_kernel<<<eb, 256, 0, stream>>>(recQ, asrc, adst, Wel[l], ael[l], alQ, srcQ);
        msg_kernel<<<(N_NODES + MSG_NPB - 1) / MSG_NPB, 256, 0, stream>>>(
            hbuf, asrc, adst, xin, ptr, srcQ, alQ, ews,
            Wel[l], ael[l], bl[l], gl[l], bel[l], xout);
        float* tmp = (float*)xin; xin = xout; xout = tmp;
    }

    pool_kernel<<<(N_NODES + PNODES - 1) / PNODES, 128, 0, stream>>>(xin, batch, pool, gcnt);
    div_kernel<<<(NB * DH + 255) / 256, 256, 0, stream>>>(pool, gcnt, outp);
}

// Round 10
// 464.240 us; speedup vs baseline: 1.1024x; 1.1024x over previous
//
#include <hip/hip_runtime.h>

#define N_NODES 50000
#define N_EDGES 800000
#define DIN 384
#define DH 128
#define NB 64
#define NEG 0.2f

// ---------------- bf16 helpers (exact bit ops) ----------------
__device__ __forceinline__ float bf2f(unsigned short u) {
    return __uint_as_float((unsigned)u << 16);
}
__device__ __forceinline__ unsigned short f2bf(float x) {  // RNE
    unsigned u = __float_as_uint(x);
    return (unsigned short)((u + 0x7fff + ((u >> 16) & 1)) >> 16);
}
using us8 = __attribute__((ext_vector_type(8))) unsigned short;

// ---------------- fused histogram + edge-weight sum ----------------
__global__ __launch_bounds__(256) void histew_kernel(const int* __restrict__ dst,
                                                     const float* __restrict__ ew,
                                                     int* __restrict__ cnt,
                                                     float* __restrict__ ews) {
    __shared__ float sred[4];
    const int tid = threadIdx.x;
    float v = 0.0f;
    for (int i = blockIdx.x * 256 + tid; i < N_EDGES; i += gridDim.x * 256) {
        atomicAdd(&cnt[dst[i]], 1);
        v += ew[i];
    }
    #pragma unroll
    for (int o = 32; o; o >>= 1) v += __shfl_down(v, o, 64);
    if ((tid & 63) == 0) sred[tid >> 6] = v;
    __syncthreads();
    if (tid == 0) atomicAdd(ews, sred[0] + sred[1] + sred[2] + sred[3]);
}

// ---------------- 3-dispatch parallel exclusive scan ----------------
__global__ void scan_a(const int* __restrict__ cnt, int* __restrict__ scanned,
                       int* __restrict__ bsums) {
    __shared__ int s[256];
    int tid = threadIdx.x;
    int i = blockIdx.x * 256 + tid;
    int v = (i < N_NODES) ? cnt[i] : 0;
    s[tid] = v; __syncthreads();
    for (int o = 1; o < 256; o <<= 1) {
        int t = (tid >= o) ? s[tid - o] : 0;
        __syncthreads();
        s[tid] += t;
        __syncthreads();
    }
    if (i < N_NODES) scanned[i] = s[tid] - v;  // exclusive
    if (tid == 255) bsums[blockIdx.x] = s[255];
}

__global__ void scan_b(int* __restrict__ bsums, int nb) {
    __shared__ int s[256];
    int tid = threadIdx.x;
    int v = (tid < nb) ? bsums[tid] : 0;
    s[tid] = v; __syncthreads();
    for (int o = 1; o < 256; o <<= 1) {
        int t = (tid >= o) ? s[tid - o] : 0;
        __syncthreads();
        s[tid] += t;
        __syncthreads();
    }
    if (tid < nb) bsums[tid] = s[tid] - v;  // exclusive
}

__global__ void scan_c(const int* __restrict__ scanned, const int* __restrict__ bsums,
                       const int* __restrict__ cnt, int* __restrict__ ptr,
                       int* __restrict__ cursor) {
    int i = blockIdx.x * 256 + threadIdx.x;
    if (i < N_NODES) {
        int p = scanned[i] + bsums[blockIdx.x];
        ptr[i] = p;
        cursor[i] = p;
        if (i == N_NODES - 1) ptr[N_NODES] = p + cnt[i];
    }
}

// fill: one 16 B record {src, dst, ew} per edge into dst-sorted order.
// ILP-4: 4 consecutive edges/thread — 3 coalesced 16 B loads, 4 independent
// atomics issued back-to-back (one latency window), then 4 scattered stores.
__global__ __launch_bounds__(256) void fill_kernel(const int* __restrict__ src,
                            const int* __restrict__ dst,
                            const float* __restrict__ ew, int* __restrict__ cursor,
                            int4* __restrict__ recQ) {
    const int e0 = (blockIdx.x * 256 + threadIdx.x) * 4;
    if (e0 + 3 < N_EDGES) {
        const int4 d4 = *(const int4*)(dst + e0);
        const int4 s4 = *(const int4*)(src + e0);
        const float4 w4 = *(const float4*)(ew + e0);
        const int p0 = atomicAdd(&cursor[d4.x], 1);
        const int p1 = atomicAdd(&cursor[d4.y], 1);
        const int p2 = atomicAdd(&cursor[d4.z], 1);
        const int p3 = atomicAdd(&cursor[d4.w], 1);
        int4 r0 = {s4.x, d4.x, __float_as_int(w4.x), 0};
        int4 r1 = {s4.y, d4.y, __float_as_int(w4.y), 0};
        int4 r2 = {s4.z, d4.z, __float_as_int(w4.z), 0};
        int4 r3 = {s4.w, d4.w, __float_as_int(w4.w), 0};
        recQ[p0] = r0; recQ[p1] = r1; recQ[p2] = r2; recQ[p3] = r3;
    } else {
        for (int e = e0; e < N_EDGES; ++e) {
            int d = dst[e];
            int p = atomicAdd(&cursor[d], 1);
            int4 r = {src[e], d, __float_as_int(ew[e]), 0};
            recQ[p] = r;
        }
    }
}

// ---------------- MFMA bf16 GEMM: C[M,128] = A[M,K] @ W[K,128] (+bias) ----------
// BF16OUT variant also computes per-row attention logits asrc/adst from the fp32
// accumulator (replaces a separate att kernel + h re-read).
template<int K, bool BF16OUT>
__global__ __launch_bounds__(256) void mfma_gemm(const float* __restrict__ A,
                                                 const float* __restrict__ W,
                                                 const float* __restrict__ bias,
                                                 void* __restrict__ Cv, int M,
                                                 const float* __restrict__ a_s,
                                                 const float* __restrict__ a_d,
                                                 float* __restrict__ asrc_o,
                                                 float* __restrict__ adst_o)
{
    constexpr int BM = 64, BK = 32;
    constexpr int LS = 40;   // LDS row stride in bf16 (80 B: conflict-spreading pad)
    __shared__ unsigned short As[BM * LS];   // [m][k]
    __shared__ unsigned short Bs[DH * LS];   // [n][k]  (W transposed)
    using short8 = __attribute__((ext_vector_type(8))) short;
    using f32x4  = __attribute__((ext_vector_type(4))) float;

    const int tid = threadIdx.x;
    const int w = tid >> 6, l = tid & 63;
    const int lane16 = l & 15, quad = l >> 4;
    const int m0 = blockIdx.x * BM;

    f32x4 acc[8] = {};

    const int ar = tid >> 2, af = tid & 3;
    int arow = m0 + ar; if (arow >= M) arow = M - 1;
    const float* Ap = A + (size_t)arow * K;
    const int bn = tid & 127, bq = tid >> 7;

    for (int k0 = 0; k0 < K; k0 += BK) {
        __syncthreads();
        #pragma unroll
        for (int i = 0; i < 2; ++i) {
            const int f4 = af + 4 * i;
            float4 v = *(const float4*)(Ap + k0 + f4 * 4);
            ushort4 u = {f2bf(v.x), f2bf(v.y), f2bf(v.z), f2bf(v.w)};
            *(ushort4*)&As[ar * LS + f4 * 4] = u;
        }
        #pragma unroll
        for (int i = 0; i < 4; ++i) {
            const int kq = bq + 2 * i;   // 0..7
            float v0 = W[(size_t)(k0 + kq * 4 + 0) * DH + bn];
            float v1 = W[(size_t)(k0 + kq * 4 + 1) * DH + bn];
            float v2 = W[(size_t)(k0 + kq * 4 + 2) * DH + bn];
            float v3 = W[(size_t)(k0 + kq * 4 + 3) * DH + bn];
            ushort4 u = {f2bf(v0), f2bf(v1), f2bf(v2), f2bf(v3)};
            *(ushort4*)&Bs[bn * LS + kq * 4] = u;
        }
        __syncthreads();
        short8 afrag = *(short8*)&As[(w * 16 + lane16) * LS + quad * 8];
        #pragma unroll
        for (int nt = 0; nt < 8; ++nt) {
            short8 bfrag = *(short8*)&Bs[(nt * 16 + lane16) * LS + quad * 8];
            acc[nt] = __builtin_amdgcn_mfma_f32_16x16x32_bf16(afrag, bfrag, acc[nt], 0, 0, 0);
        }
    }

    const int orow0 = m0 + w * 16 + quad * 4;
    #pragma unroll
    for (int nt = 0; nt < 8; ++nt) {
        const int col = nt * 16 + lane16;
        const float bv = BF16OUT ? 0.0f : bias[col];
        #pragma unroll
        for (int r = 0; r < 4; ++r) {
            const int row = orow0 + r;
            if (row < M) {
                if constexpr (BF16OUT)
                    ((unsigned short*)Cv)[(size_t)row * DH + col] = f2bf(acc[nt][r]);
                else
                    ((float*)Cv)[(size_t)row * DH + col] = acc[nt][r] + bv;
            }
        }
    }

    if constexpr (BF16OUT) {
        // attention logits: asrc[row][hd] = sum_{f in head} h[row][hd*32+f]*a_s[hd][f]
        float psh[4][4] = {}, pdh[4][4] = {};   // [head][r]
        #pragma unroll
        for (int nt = 0; nt < 8; ++nt) {
            const int hd = nt >> 1;
            const float asv = a_s[nt * 16 + lane16];
            const float adv = a_d[nt * 16 + lane16];
            #pragma unroll
            for (int r = 0; r < 4; ++r) {
                psh[hd][r] = fmaf(acc[nt][r], asv, psh[hd][r]);
                pdh[hd][r] = fmaf(acc[nt][r], adv, pdh[hd][r]);
            }
        }
        #pragma unroll
        for (int o = 1; o < 16; o <<= 1) {
            #pragma unroll
            for (int hd = 0; hd < 4; ++hd)
                #pragma unroll
                for (int r = 0; r < 4; ++r) {
                    psh[hd][r] += __shfl_xor(psh[hd][r], o, 64);
                    pdh[hd][r] += __shfl_xor(pdh[hd][r], o, 64);
                }
        }
        if (lane16 == 0) {
            #pragma unroll
            for (int r = 0; r < 4; ++r) {
                const int row = orow0 + r;
                if (row < M) {
                    float4 o1 = {psh[0][r], psh[1][r], psh[2][r], psh[3][r]};
                    float4 o2 = {pdh[0][r], pdh[1][r], pdh[2][r], pdh[3][r]};
                    *(float4*)(asrc_o + (size_t)row * 4) = o1;
                    *(float4*)(adst_o + (size_t)row * 4) = o2;
                }
            }
        }
    }
}

// ---------------- edge-parallel alpha from records ----------------
__global__ __launch_bounds__(256) void alpha_kernel(
    const int4* __restrict__ recQ, const float* __restrict__ asrc,
    const float* __restrict__ adst, const float* __restrict__ Wedge,
    const float* __restrict__ aedge, float* __restrict__ alQ,
    int* __restrict__ srcQ)
{
    const int l = threadIdx.x & 63;
    float p0 = Wedge[l] * aedge[l];
    float p1 = Wedge[l + 64] * aedge[l + 64];
    #pragma unroll
    for (int o = 1; o < 32; o <<= 1) { p0 += __shfl_xor(p0, o, 64); p1 += __shfl_xor(p1, o, 64); }
    const float cc0 = __shfl(p0, 0, 64), cc1 = __shfl(p0, 32, 64);
    const float cc2 = __shfl(p1, 0, 64), cc3 = __shfl(p1, 32, 64);

    const int e = blockIdx.x * 256 + threadIdx.x;
    if (e >= N_EDGES) return;
    const int4 r = recQ[e];
    const int s = r.x, d = r.y;
    const float wgt = __int_as_float(r.z);
    srcQ[e] = s;
    const float4 a4 = *(const float4*)(asrc + (size_t)s * 4);
    const float4 b4 = *(const float4*)(adst + (size_t)d * 4);
    float v0 = a4.x + b4.x + wgt * cc0;
    float v1 = a4.y + b4.y + wgt * cc1;
    float v2 = a4.z + b4.z + wgt * cc2;
    float v3 = a4.w + b4.w + wgt * cc3;
    v0 = v0 > 0.f ? v0 : NEG * v0;
    v1 = v1 > 0.f ? v1 : NEG * v1;
    v2 = v2 > 0.f ? v2 : NEG * v2;
    v3 = v3 > 0.f ? v3 : NEG * v3;
    // |alpha| << 1 -> exp without max-shift is exact softmax (shift-invariant)
    float4 o4 = {__expf(v0), __expf(v1), __expf(v2), __expf(v3)};
    *(float4*)(alQ + (size_t)e * 4) = o4;
}

// ---------------- msg: pure gather, LDS-free, 4 nodes / 256-thr block ----------
#define MSG_NPB 4
__global__ __launch_bounds__(256) void msg_kernel(
    const unsigned short* __restrict__ h, const float* __restrict__ asrc,
    const float* __restrict__ adst, const float* __restrict__ xres,
    const int* __restrict__ indptr, const int* __restrict__ srcQ,
    const float* __restrict__ alQ, const float* __restrict__ ewsum,
    const float* __restrict__ Wedge, const float* __restrict__ aedge,
    const float* __restrict__ bias, const float* __restrict__ gamma,
    const float* __restrict__ beta, float* __restrict__ xout)
{
    const int l = threadIdx.x & 63;
    const int n = blockIdx.x * MSG_NPB + (threadIdx.x >> 6);
    if (n >= N_NODES) return;
    const int sub2 = l >> 4, c8 = l & 15, hd8 = c8 >> 2;

    // c[k] = dot(We_k, ae_k) for self-loop logit
    float p0 = Wedge[l] * aedge[l];
    float p1 = Wedge[l + 64] * aedge[l + 64];
    #pragma unroll
    for (int o = 1; o < 32; o <<= 1) { p0 += __shfl_xor(p0, o, 64); p1 += __shfl_xor(p1, o, 64); }
    float cc[4];
    cc[0] = __shfl(p0, 0, 64);  cc[1] = __shfl(p0, 32, 64);
    cc[2] = __shfl(p1, 0, 64);  cc[3] = __shfl(p1, 32, 64);

    const float4 ad4 = *(const float4*)(adst + (size_t)n * 4);
    const float4 as4 = *(const float4*)(asrc + (size_t)n * 4);
    const float ewm = ewsum[0] * (1.0f / N_EDGES);
    float pv0[4];
    {
        const float av[4] = {as4.x, as4.y, as4.z, as4.w};
        const float dv[4] = {ad4.x, ad4.y, ad4.z, ad4.w};
        #pragma unroll
        for (int k = 0; k < 4; ++k) {
            float a0 = av[k] + dv[k] + ewm * cc[k];
            a0 = a0 > 0.f ? a0 : NEG * a0;
            pv0[k] = __expf(a0);
        }
    }

    float dsum = 0.f;
    float acc8[8] = {};
    const unsigned short* hb = h + c8 * 8;
    if (sub2 == 0) {
        us8 u = *(const us8*)(hb + (size_t)n * DH);
        const float f = pv0[hd8];
        #pragma unroll
        for (int i = 0; i < 8; ++i) acc8[i] = f * bf2f(u[i]);
    }

    const int st = indptr[n], deg = indptr[n + 1] - st;
    const int* sq = srcQ + st;
    const float* aq = alQ + (size_t)st * 4 + hd8;
    int e = sub2;
    for (; e + 12 < deg; e += 16) {
        const int s0 = sq[e],     s1 = sq[e + 4];
        const int s2 = sq[e + 8], s3 = sq[e + 12];
        const float c0 = aq[(size_t)e * 4],        c1 = aq[(size_t)(e + 4) * 4];
        const float c2 = aq[(size_t)(e + 8) * 4],  c3 = aq[(size_t)(e + 12) * 4];
        us8 u0 = *(const us8*)(hb + (size_t)s0 * DH);
        us8 u1 = *(const us8*)(hb + (size_t)s1 * DH);
        us8 u2 = *(const us8*)(hb + (size_t)s2 * DH);
        us8 u3 = *(const us8*)(hb + (size_t)s3 * DH);
        dsum += c0 + c1 + c2 + c3;
        #pragma unroll
        for (int i = 0; i < 8; ++i)
            acc8[i] = fmaf(c0, bf2f(u0[i]),
                      fmaf(c1, bf2f(u1[i]),
                      fmaf(c2, bf2f(u2[i]),
                      fmaf(c3, bf2f(u3[i]), acc8[i]))));
    }
    for (; e < deg; e += 4) {
        const int s = sq[e];
        const float coef = aq[(size_t)e * 4];
        us8 u = *(const us8*)(hb + (size_t)s * DH);
        dsum += coef;
        #pragma unroll
        for (int i = 0; i < 8; ++i) acc8[i] = fmaf(coef, bf2f(u[i]), acc8[i]);
    }

    // reduce over the 4 edge-parity groups (bits 4,5 of lane id)
    #pragma unroll
    for (int i = 0; i < 8; ++i) {
        acc8[i] += __shfl_xor(acc8[i], 16, 64);
        acc8[i] += __shfl_xor(acc8[i], 32, 64);
    }
    dsum += __shfl_xor(dsum, 16, 64);
    dsum += __shfl_xor(dsum, 32, 64);

    const float inv_d = 1.0f / (dsum + pv0[hd8] + 1e-16f);
    const float4 b4a = *(const float4*)(bias + c8 * 8);
    const float4 b4b = *(const float4*)(bias + c8 * 8 + 4);
    float y[8];
    y[0] = acc8[0] * inv_d + b4a.x; y[1] = acc8[1] * inv_d + b4a.y;
    y[2] = acc8[2] * inv_d + b4a.z; y[3] = acc8[3] * inv_d + b4a.w;
    y[4] = acc8[4] * inv_d + b4b.x; y[5] = acc8[5] * inv_d + b4b.y;
    y[6] = acc8[6] * inv_d + b4b.z; y[7] = acc8[7] * inv_d + b4b.w;

    float s1 = 0.f, s2 = 0.f;
    #pragma unroll
    for (int i = 0; i < 8; ++i) { s1 += y[i]; s2 += y[i] * y[i]; }
    #pragma unroll
    for (int o = 1; o < 16; o <<= 1) {
        s1 += __shfl_xor(s1, o, 64);
        s2 += __shfl_xor(s2, o, 64);
    }
    const float mu = s1 * (1.0f / DH);
    const float var = s2 * (1.0f / DH) - mu * mu;
    const float rs = rsqrtf(var + 1e-5f);

    if (sub2 == 0) {
        const float4 g4a = *(const float4*)(gamma + c8 * 8);
        const float4 g4b = *(const float4*)(gamma + c8 * 8 + 4);
        const float4 e4a = *(const float4*)(beta + c8 * 8);
        const float4 e4b = *(const float4*)(beta + c8 * 8 + 4);
        const float4 r4a = *(const float4*)(xres + (size_t)n * DH + c8 * 8);
        const float4 r4b = *(const float4*)(xres + (size_t)n * DH + c8 * 8 + 4);
        const float gv[8] = {g4a.x, g4a.y, g4a.z, g4a.w, g4b.x, g4b.y, g4b.z, g4b.w};
        const float ev[8] = {e4a.x, e4a.y, e4a.z, e4a.w, e4b.x, e4b.y, e4b.z, e4b.w};
        const float rv[8] = {r4a.x, r4a.y, r4a.z, r4a.w, r4b.x, r4b.y, r4b.z, r4b.w};
        float z[8];
        #pragma unroll
        for (int i = 0; i < 8; ++i) {
            float t = (y[i] - mu) * rs * gv[i] + ev[i];
            z[i] = (t > 0.f ? t : __expf(t) - 1.0f) + rv[i];
        }
        *(float4*)(xout + (size_t)n * DH + c8 * 8)     = *(float4*)&z[0];
        *(float4*)(xout + (size_t)n * DH + c8 * 8 + 4) = *(float4*)&z[4];
    }
}

// ---------------- global mean pool ----------------
#define PNODES 64
__global__ __launch_bounds__(128) void pool_kernel(const float* __restrict__ x,
        const int* __restrict__ batch, float* __restrict__ pool, int* __restrict__ gcnt)
{
    int t = threadIdx.x;
    int n0 = blockIdx.x * PNODES;
    if (n0 >= N_NODES) return;
    int n1 = min(n0 + PNODES, N_NODES);
    float acc = 0.f; int cn = 0;
    int curb = batch[n0];
    for (int n = n0; n < n1; ++n) {
        int b = batch[n];
        if (b != curb) {
            atomicAdd(&pool[(size_t)curb * DH + t], acc);
            if (t == 0) atomicAdd(&gcnt[curb], cn);
            acc = 0.f; cn = 0; curb = b;
        }
        acc += x[(size_t)n * DH + t];
        ++cn;
    }
    atomicAdd(&pool[(size_t)curb * DH + t], acc);
    if (t == 0) atomicAdd(&gcnt[curb], cn);
}

__global__ void div_kernel(const float* __restrict__ pool, const int* __restrict__ gcnt,
                           float* __restrict__ out)
{
    int i = blockIdx.x * blockDim.x + threadIdx.x;
    if (i < NB * DH) {
        float c = (float)gcnt[i >> 7];
        out[i] = pool[i] / fmaxf(c, 1.0f);
    }
}

// ---------------- launch ----------------
extern "C" void kernel_launch(void* const* d_in, const int* in_sizes, int n_in,
                              void* d_out, int out_size, void* d_ws, size_t ws_size,
                              hipStream_t stream)
{
    const float* nf    = (const float*)d_in[0];
    const int*   esrc  = (const int*)d_in[1];
    const int*   edst  = esrc + N_EDGES;
    const float* ew    = (const float*)d_in[2];
    const int*   batch = (const int*)d_in[3];
    const float* Wp    = (const float*)d_in[4];
    const float* bp    = (const float*)d_in[5];
    const float* Wl[2]  = {(const float*)d_in[6],  (const float*)d_in[14]};
    const float* asl[2] = {(const float*)d_in[7],  (const float*)d_in[15]};
    const float* adl[2] = {(const float*)d_in[8],  (const float*)d_in[16]};
    const float* Wel[2] = {(const float*)d_in[9],  (const float*)d_in[17]};
    const float* ael[2] = {(const float*)d_in[10], (const float*)d_in[18]};
    const float* bl[2]  = {(const float*)d_in[11], (const float*)d_in[19]};
    const float* gl[2]  = {(const float*)d_in[12], (const float*)d_in[20]};
    const float* bel[2] = {(const float*)d_in[13], (const float*)d_in[21]};
    float* outp = (float*)d_out;

    char* w = (char*)d_ws;
    auto alloc = [&](size_t bytes) { char* p = w; w += (bytes + 255) & ~255ull; return p; };
    float* xA     = (float*)alloc((size_t)N_NODES * DH * 4);
    float* xB     = (float*)alloc((size_t)N_NODES * DH * 4);
    unsigned short* hbuf = (unsigned short*)alloc((size_t)N_NODES * DH * 2);
    float* asrc   = (float*)alloc((size_t)N_NODES * 4 * 4);
    float* adst   = (float*)alloc((size_t)N_NODES * 4 * 4);
    // contiguous zero-init group: pool | gcnt | ews | cnt  (one memset)
    float* pool   = (float*)alloc((size_t)NB * DH * 4);     // 32768 B
    int* gcnt     = (int*)alloc(256);
    float* ews    = (float*)alloc(256);
    int* cnt      = (int*)alloc((size_t)N_NODES * 4);
    int* scanned  = (int*)alloc((size_t)N_NODES * 4);
    int* bsums    = (int*)alloc(1024);
    int* ptr      = (int*)alloc((size_t)(N_NODES + 8) * 4);
    int* cursor   = (int*)alloc((size_t)N_NODES * 4);
    int* srcQ     = (int*)alloc((size_t)N_EDGES * 4);
    int4* recQ    = (int4*)alloc((size_t)N_EDGES * 16);
    float* alQ    = (float*)alloc((size_t)N_EDGES * 4 * 4);

    hipMemsetAsync(pool, 0, (size_t)NB * DH * 4 + 256 + 256 + (size_t)N_NODES * 4, stream);

    const int eb = (N_EDGES + 255) / 256;  // 3125
    const int sb = (N_NODES + 255) / 256;  // 196

    histew_kernel<<<1024, 256, 0, stream>>>(edst, ew, cnt, ews);
    scan_a<<<sb, 256, 0, stream>>>(cnt, scanned, bsums);
    scan_b<<<1, 256, 0, stream>>>(bsums, sb);
    scan_c<<<sb, 256, 0, stream>>>(scanned, bsums, cnt, ptr, cursor);
    fill_kernel<<<(N_EDGES / 4 + 255) / 256, 256, 0, stream>>>(esrc, edst, ew, cursor, recQ);

    const int gb = (N_NODES + 63) / 64;  // 782
    mfma_gemm<DIN, false><<<gb, 256, 0, stream>>>(nf, Wp, bp, xA, N_NODES,
                                                  nullptr, nullptr, nullptr, nullptr);

    const float* xin = xA;
    float* xout = xB;
    for (int l = 0; l < 2; ++l) {
        mfma_gemm<DH, true><<<gb, 256, 0, stream>>>(xin, Wl[l], nullptr, hbuf, N_NODES,
                                                    asl[l], adl[l], asrc, adst);
        alpha_kernel<<<eb, 256, 0, stream>>>(recQ, asrc, adst, Wel[l], ael[l], alQ, srcQ);
        msg_kernel<<<(N_NODES + MSG_NPB - 1) / MSG_NPB, 256, 0, stream>>>(
            hbuf, asrc, adst, xin, ptr, srcQ, alQ, ews,
            Wel[l], ael[l], bl[l], gl[l], bel[l], xout);
        float* tmp = (float*)xin; xin = xout; xout = tmp;
    }

    pool_kernel<<<(N_NODES + PNODES - 1) / PNODES, 128, 0, stream>>>(xin, batch, pool, gcnt);
    div_kernel<<<(NB * DH + 255) / 256, 256, 0, stream>>>(pool, gcnt, outp);
}

// Round 11
// 425.534 us; speedup vs baseline: 1.2026x; 1.0910x over previous
//
#include <hip/hip_runtime.h>

#define N_NODES 50000
#define N_EDGES 800000
#define DIN 384
#define DH 128
#define NB 64
#define NEG 0.2f

// ---------------- bf16 helpers (exact bit ops) ----------------
__device__ __forceinline__ float bf2f(unsigned short u) {
    return __uint_as_float((unsigned)u << 16);
}
__device__ __forceinline__ unsigned short f2bf(float x) {  // RNE
    unsigned u = __float_as_uint(x);
    return (unsigned short)((u + 0x7fff + ((u >> 16) & 1)) >> 16);
}
using us8 = __attribute__((ext_vector_type(8))) unsigned short;

// ---------------- fused histogram + rank capture + edge-weight sum ----------
// rank[e] = position of edge e within its dst bucket (atomicAdd return value —
// the atomic is paid here anyway; capturing old value is free and makes the
// downstream fill atomic-free).
__global__ __launch_bounds__(256) void histew_kernel(const int* __restrict__ dst,
                                                     const float* __restrict__ ew,
                                                     int* __restrict__ cnt,
                                                     int* __restrict__ rank,
                                                     float* __restrict__ ews) {
    __shared__ float sred[4];
    const int tid = threadIdx.x;
    float v = 0.0f;
    for (int i = blockIdx.x * 256 + tid; i < N_EDGES; i += gridDim.x * 256) {
        rank[i] = atomicAdd(&cnt[dst[i]], 1);
        v += ew[i];
    }
    #pragma unroll
    for (int o = 32; o; o >>= 1) v += __shfl_down(v, o, 64);
    if ((tid & 63) == 0) sred[tid >> 6] = v;
    __syncthreads();
    if (tid == 0) atomicAdd(ews, sred[0] + sred[1] + sred[2] + sred[3]);
}

// ---------------- 3-dispatch parallel exclusive scan ----------------
__global__ void scan_a(const int* __restrict__ cnt, int* __restrict__ scanned,
                       int* __restrict__ bsums) {
    __shared__ int s[256];
    int tid = threadIdx.x;
    int i = blockIdx.x * 256 + tid;
    int v = (i < N_NODES) ? cnt[i] : 0;
    s[tid] = v; __syncthreads();
    for (int o = 1; o < 256; o <<= 1) {
        int t = (tid >= o) ? s[tid - o] : 0;
        __syncthreads();
        s[tid] += t;
        __syncthreads();
    }
    if (i < N_NODES) scanned[i] = s[tid] - v;  // exclusive
    if (tid == 255) bsums[blockIdx.x] = s[255];
}

__global__ void scan_b(int* __restrict__ bsums, int nb) {
    __shared__ int s[256];
    int tid = threadIdx.x;
    int v = (tid < nb) ? bsums[tid] : 0;
    s[tid] = v; __syncthreads();
    for (int o = 1; o < 256; o <<= 1) {
        int t = (tid >= o) ? s[tid - o] : 0;
        __syncthreads();
        s[tid] += t;
        __syncthreads();
    }
    if (tid < nb) bsums[tid] = s[tid] - v;  // exclusive
}

__global__ void scan_c(const int* __restrict__ scanned, const int* __restrict__ bsums,
                       const int* __restrict__ cnt, int* __restrict__ ptr) {
    int i = blockIdx.x * 256 + threadIdx.x;
    if (i < N_NODES) {
        int p = scanned[i] + bsums[blockIdx.x];
        ptr[i] = p;
        if (i == N_NODES - 1) ptr[N_NODES] = p + cnt[i];
    }
}

// fill: atomic-free. p = ptr[dst] + rank (rank captured in histew). Scattered
// 16 B stores are fire-and-forget (no dependent consumer -> no waitcnt stall).
__global__ __launch_bounds__(256) void fill_kernel(const int* __restrict__ src,
                            const int* __restrict__ dst,
                            const float* __restrict__ ew,
                            const int* __restrict__ rank,
                            const int* __restrict__ ptr,
                            int4* __restrict__ recQ) {
    const int e0 = (blockIdx.x * 256 + threadIdx.x) * 4;
    if (e0 >= N_EDGES) return;
    const int4 d4 = *(const int4*)(dst + e0);
    const int4 s4 = *(const int4*)(src + e0);
    const int4 r4 = *(const int4*)(rank + e0);
    const float4 w4 = *(const float4*)(ew + e0);
    const int p0 = ptr[d4.x] + r4.x;
    const int p1 = ptr[d4.y] + r4.y;
    const int p2 = ptr[d4.z] + r4.z;
    const int p3 = ptr[d4.w] + r4.w;
    int4 q0 = {s4.x, d4.x, __float_as_int(w4.x), 0};
    int4 q1 = {s4.y, d4.y, __float_as_int(w4.y), 0};
    int4 q2 = {s4.z, d4.z, __float_as_int(w4.z), 0};
    int4 q3 = {s4.w, d4.w, __float_as_int(w4.w), 0};
    recQ[p0] = q0; recQ[p1] = q1; recQ[p2] = q2; recQ[p3] = q3;
}

// ---------------- MFMA bf16 GEMM: C[M,128] = A[M,K] @ W[K,128] (+bias) ----------
// BF16OUT variant also computes per-row attention logits asrc/adst from the fp32
// accumulator (replaces a separate att kernel + h re-read).
template<int K, bool BF16OUT>
__global__ __launch_bounds__(256) void mfma_gemm(const float* __restrict__ A,
                                                 const float* __restrict__ W,
                                                 const float* __restrict__ bias,
                                                 void* __restrict__ Cv, int M,
                                                 const float* __restrict__ a_s,
                                                 const float* __restrict__ a_d,
                                                 float* __restrict__ asrc_o,
                                                 float* __restrict__ adst_o)
{
    constexpr int BM = 64, BK = 32;
    constexpr int LS = 40;   // LDS row stride in bf16 (80 B: conflict-spreading pad)
    __shared__ unsigned short As[BM * LS];   // [m][k]
    __shared__ unsigned short Bs[DH * LS];   // [n][k]  (W transposed)
    using short8 = __attribute__((ext_vector_type(8))) short;
    using f32x4  = __attribute__((ext_vector_type(4))) float;

    const int tid = threadIdx.x;
    const int w = tid >> 6, l = tid & 63;
    const int lane16 = l & 15, quad = l >> 4;
    const int m0 = blockIdx.x * BM;

    f32x4 acc[8] = {};

    const int ar = tid >> 2, af = tid & 3;
    int arow = m0 + ar; if (arow >= M) arow = M - 1;
    const float* Ap = A + (size_t)arow * K;
    const int bn = tid & 127, bq = tid >> 7;

    for (int k0 = 0; k0 < K; k0 += BK) {
        __syncthreads();
        #pragma unroll
        for (int i = 0; i < 2; ++i) {
            const int f4 = af + 4 * i;
            float4 v = *(const float4*)(Ap + k0 + f4 * 4);
            ushort4 u = {f2bf(v.x), f2bf(v.y), f2bf(v.z), f2bf(v.w)};
            *(ushort4*)&As[ar * LS + f4 * 4] = u;
        }
        #pragma unroll
        for (int i = 0; i < 4; ++i) {
            const int kq = bq + 2 * i;   // 0..7
            float v0 = W[(size_t)(k0 + kq * 4 + 0) * DH + bn];
            float v1 = W[(size_t)(k0 + kq * 4 + 1) * DH + bn];
            float v2 = W[(size_t)(k0 + kq * 4 + 2) * DH + bn];
            float v3 = W[(size_t)(k0 + kq * 4 + 3) * DH + bn];
            ushort4 u = {f2bf(v0), f2bf(v1), f2bf(v2), f2bf(v3)};
            *(ushort4*)&Bs[bn * LS + kq * 4] = u;
        }
        __syncthreads();
        short8 afrag = *(short8*)&As[(w * 16 + lane16) * LS + quad * 8];
        #pragma unroll
        for (int nt = 0; nt < 8; ++nt) {
            short8 bfrag = *(short8*)&Bs[(nt * 16 + lane16) * LS + quad * 8];
            acc[nt] = __builtin_amdgcn_mfma_f32_16x16x32_bf16(afrag, bfrag, acc[nt], 0, 0, 0);
        }
    }

    const int orow0 = m0 + w * 16 + quad * 4;
    #pragma unroll
    for (int nt = 0; nt < 8; ++nt) {
        const int col = nt * 16 + lane16;
        const float bv = BF16OUT ? 0.0f : bias[col];
        #pragma unroll
        for (int r = 0; r < 4; ++r) {
            const int row = orow0 + r;
            if (row < M) {
                if constexpr (BF16OUT)
                    ((unsigned short*)Cv)[(size_t)row * DH + col] = f2bf(acc[nt][r]);
                else
                    ((float*)Cv)[(size_t)row * DH + col] = acc[nt][r] + bv;
            }
        }
    }

    if constexpr (BF16OUT) {
        // attention logits: asrc[row][hd] = sum_{f in head} h[row][hd*32+f]*a_s[hd][f]
        float psh[4][4] = {}, pdh[4][4] = {};   // [head][r]
        #pragma unroll
        for (int nt = 0; nt < 8; ++nt) {
            const int hd = nt >> 1;
            const float asv = a_s[nt * 16 + lane16];
            const float adv = a_d[nt * 16 + lane16];
            #pragma unroll
            for (int r = 0; r < 4; ++r) {
                psh[hd][r] = fmaf(acc[nt][r], asv, psh[hd][r]);
                pdh[hd][r] = fmaf(acc[nt][r], adv, pdh[hd][r]);
            }
        }
        #pragma unroll
        for (int o = 1; o < 16; o <<= 1) {
            #pragma unroll
            for (int hd = 0; hd < 4; ++hd)
                #pragma unroll
                for (int r = 0; r < 4; ++r) {
                    psh[hd][r] += __shfl_xor(psh[hd][r], o, 64);
                    pdh[hd][r] += __shfl_xor(pdh[hd][r], o, 64);
                }
        }
        if (lane16 == 0) {
            #pragma unroll
            for (int r = 0; r < 4; ++r) {
                const int row = orow0 + r;
                if (row < M) {
                    float4 o1 = {psh[0][r], psh[1][r], psh[2][r], psh[3][r]};
                    float4 o2 = {pdh[0][r], pdh[1][r], pdh[2][r], pdh[3][r]};
                    *(float4*)(asrc_o + (size_t)row * 4) = o1;
                    *(float4*)(adst_o + (size_t)row * 4) = o2;
                }
            }
        }
    }
}

// ---------------- edge-parallel alpha from records ----------------
__global__ __launch_bounds__(256) void alpha_kernel(
    const int4* __restrict__ recQ, const float* __restrict__ asrc,
    const float* __restrict__ adst, const float* __restrict__ Wedge,
    const float* __restrict__ aedge, float* __restrict__ alQ,
    int* __restrict__ srcQ)
{
    const int l = threadIdx.x & 63;
    float p0 = Wedge[l] * aedge[l];
    float p1 = Wedge[l + 64] * aedge[l + 64];
    #pragma unroll
    for (int o = 1; o < 32; o <<= 1) { p0 += __shfl_xor(p0, o, 64); p1 += __shfl_xor(p1, o, 64); }
    const float cc0 = __shfl(p0, 0, 64), cc1 = __shfl(p0, 32, 64);
    const float cc2 = __shfl(p1, 0, 64), cc3 = __shfl(p1, 32, 64);

    const int e = blockIdx.x * 256 + threadIdx.x;
    if (e >= N_EDGES) return;
    const int4 r = recQ[e];
    const int s = r.x, d = r.y;
    const float wgt = __int_as_float(r.z);
    srcQ[e] = s;
    const float4 a4 = *(const float4*)(asrc + (size_t)s * 4);
    const float4 b4 = *(const float4*)(adst + (size_t)d * 4);
    float v0 = a4.x + b4.x + wgt * cc0;
    float v1 = a4.y + b4.y + wgt * cc1;
    float v2 = a4.z + b4.z + wgt * cc2;
    float v3 = a4.w + b4.w + wgt * cc3;
    v0 = v0 > 0.f ? v0 : NEG * v0;
    v1 = v1 > 0.f ? v1 : NEG * v1;
    v2 = v2 > 0.f ? v2 : NEG * v2;
    v3 = v3 > 0.f ? v3 : NEG * v3;
    // |alpha| << 1 -> exp without max-shift is exact softmax (shift-invariant)
    float4 o4 = {__expf(v0), __expf(v1), __expf(v2), __expf(v3)};
    *(float4*)(alQ + (size_t)e * 4) = o4;
}

// ---------------- msg: pure gather, LDS-free, 4 nodes / 256-thr block ----------
#define MSG_NPB 4
__global__ __launch_bounds__(256) void msg_kernel(
    const unsigned short* __restrict__ h, const float* __restrict__ asrc,
    const float* __restrict__ adst, const float* __restrict__ xres,
    const int* __restrict__ indptr, const int* __restrict__ srcQ,
    const float* __restrict__ alQ, const float* __restrict__ ewsum,
    const float* __restrict__ Wedge, const float* __restrict__ aedge,
    const float* __restrict__ bias, const float* __restrict__ gamma,
    const float* __restrict__ beta, float* __restrict__ xout)
{
    const int l = threadIdx.x & 63;
    const int n = blockIdx.x * MSG_NPB + (threadIdx.x >> 6);
    if (n >= N_NODES) return;
    const int sub2 = l >> 4, c8 = l & 15, hd8 = c8 >> 2;

    // c[k] = dot(We_k, ae_k) for self-loop logit
    float p0 = Wedge[l] * aedge[l];
    float p1 = Wedge[l + 64] * aedge[l + 64];
    #pragma unroll
    for (int o = 1; o < 32; o <<= 1) { p0 += __shfl_xor(p0, o, 64); p1 += __shfl_xor(p1, o, 64); }
    float cc[4];
    cc[0] = __shfl(p0, 0, 64);  cc[1] = __shfl(p0, 32, 64);
    cc[2] = __shfl(p1, 0, 64);  cc[3] = __shfl(p1, 32, 64);

    const float4 ad4 = *(const float4*)(adst + (size_t)n * 4);
    const float4 as4 = *(const float4*)(asrc + (size_t)n * 4);
    const float ewm = ewsum[0] * (1.0f / N_EDGES);
    float pv0[4];
    {
        const float av[4] = {as4.x, as4.y, as4.z, as4.w};
        const float dv[4] = {ad4.x, ad4.y, ad4.z, ad4.w};
        #pragma unroll
        for (int k = 0; k < 4; ++k) {
            float a0 = av[k] + dv[k] + ewm * cc[k];
            a0 = a0 > 0.f ? a0 : NEG * a0;
            pv0[k] = __expf(a0);
        }
    }

    float dsum = 0.f;
    float acc8[8] = {};
    const unsigned short* hb = h + c8 * 8;
    if (sub2 == 0) {
        us8 u = *(const us8*)(hb + (size_t)n * DH);
        const float f = pv0[hd8];
        #pragma unroll
        for (int i = 0; i < 8; ++i) acc8[i] = f * bf2f(u[i]);
    }

    const int st = indptr[n], deg = indptr[n + 1] - st;
    const int* sq = srcQ + st;
    const float* aq = alQ + (size_t)st * 4 + hd8;
    int e = sub2;
    for (; e + 12 < deg; e += 16) {
        const int s0 = sq[e],     s1 = sq[e + 4];
        const int s2 = sq[e + 8], s3 = sq[e + 12];
        const float c0 = aq[(size_t)e * 4],        c1 = aq[(size_t)(e + 4) * 4];
        const float c2 = aq[(size_t)(e + 8) * 4],  c3 = aq[(size_t)(e + 12) * 4];
        us8 u0 = *(const us8*)(hb + (size_t)s0 * DH);
        us8 u1 = *(const us8*)(hb + (size_t)s1 * DH);
        us8 u2 = *(const us8*)(hb + (size_t)s2 * DH);
        us8 u3 = *(const us8*)(hb + (size_t)s3 * DH);
        dsum += c0 + c1 + c2 + c3;
        #pragma unroll
        for (int i = 0; i < 8; ++i)
            acc8[i] = fmaf(c0, bf2f(u0[i]),
                      fmaf(c1, bf2f(u1[i]),
                      fmaf(c2, bf2f(u2[i]),
                      fmaf(c3, bf2f(u3[i]), acc8[i]))));
    }
    for (; e < deg; e += 4) {
        const int s = sq[e];
        const float coef = aq[(size_t)e * 4];
        us8 u = *(const us8*)(hb + (size_t)s * DH);
        dsum += coef;
        #pragma unroll
        for (int i = 0; i < 8; ++i) acc8[i] = fmaf(coef, bf2f(u[i]), acc8[i]);
    }

    // reduce over the 4 edge-parity groups (bits 4,5 of lane id)
    #pragma unroll
    for (int i = 0; i < 8; ++i) {
        acc8[i] += __shfl_xor(acc8[i], 16, 64);
        acc8[i] += __shfl_xor(acc8[i], 32, 64);
    }
    dsum += __shfl_xor(dsum, 16, 64);
    dsum += __shfl_xor(dsum, 32, 64);

    const float inv_d = 1.0f / (dsum + pv0[hd8] + 1e-16f);
    const float4 b4a = *(const float4*)(bias + c8 * 8);
    const float4 b4b = *(const float4*)(bias + c8 * 8 + 4);
    float y[8];
    y[0] = acc8[0] * inv_d + b4a.x; y[1] = acc8[1] * inv_d + b4a.y;
    y[2] = acc8[2] * inv_d + b4a.z; y[3] = acc8[3] * inv_d + b4a.w;
    y[4] = acc8[4] * inv_d + b4b.x; y[5] = acc8[5] * inv_d + b4b.y;
    y[6] = acc8[6] * inv_d + b4b.z; y[7] = acc8[7] * inv_d + b4b.w;

    float s1 = 0.f, s2 = 0.f;
    #pragma unroll
    for (int i = 0; i < 8; ++i) { s1 += y[i]; s2 += y[i] * y[i]; }
    #pragma unroll
    for (int o = 1; o < 16; o <<= 1) {
        s1 += __shfl_xor(s1, o, 64);
        s2 += __shfl_xor(s2, o, 64);
    }
    const float mu = s1 * (1.0f / DH);
    const float var = s2 * (1.0f / DH) - mu * mu;
    const float rs = rsqrtf(var + 1e-5f);

    if (sub2 == 0) {
        const float4 g4a = *(const float4*)(gamma + c8 * 8);
        const float4 g4b = *(const float4*)(gamma + c8 * 8 + 4);
        const float4 e4a = *(const float4*)(beta + c8 * 8);
        const float4 e4b = *(const float4*)(beta + c8 * 8 + 4);
        const float4 r4a = *(const float4*)(xres + (size_t)n * DH + c8 * 8);
        const float4 r4b = *(const float4*)(xres + (size_t)n * DH + c8 * 8 + 4);
        const float gv[8] = {g4a.x, g4a.y, g4a.z, g4a.w, g4b.x, g4b.y, g4b.z, g4b.w};
        const float ev[8] = {e4a.x, e4a.y, e4a.z, e4a.w, e4b.x, e4b.y, e4b.z, e4b.w};
        const float rv[8] = {r4a.x, r4a.y, r4a.z, r4a.w, r4b.x, r4b.y, r4b.z, r4b.w};
        float z[8];
        #pragma unroll
        for (int i = 0; i < 8; ++i) {
            float t = (y[i] - mu) * rs * gv[i] + ev[i];
            z[i] = (t > 0.f ? t : __expf(t) - 1.0f) + rv[i];
        }
        *(float4*)(xout + (size_t)n * DH + c8 * 8)     = *(float4*)&z[0];
        *(float4*)(xout + (size_t)n * DH + c8 * 8 + 4) = *(float4*)&z[4];
    }
}

// ---------------- global mean pool ----------------
#define PNODES 64
__global__ __launch_bounds__(128) void pool_kernel(const float* __restrict__ x,
        const int* __restrict__ batch, float* __restrict__ pool, int* __restrict__ gcnt)
{
    int t = threadIdx.x;
    int n0 = blockIdx.x * PNODES;
    if (n0 >= N_NODES) return;
    int n1 = min(n0 + PNODES, N_NODES);
    float acc = 0.f; int cn = 0;
    int curb = batch[n0];
    for (int n = n0; n < n1; ++n) {
        int b = batch[n];
        if (b != curb) {
            atomicAdd(&pool[(size_t)curb * DH + t], acc);
            if (t == 0) atomicAdd(&gcnt[curb], cn);
            acc = 0.f; cn = 0; curb = b;
        }
        acc += x[(size_t)n * DH + t];
        ++cn;
    }
    atomicAdd(&pool[(size_t)curb * DH + t], acc);
    if (t == 0) atomicAdd(&gcnt[curb], cn);
}

__global__ void div_kernel(const float* __restrict__ pool, const int* __restrict__ gcnt,
                           float* __restrict__ out)
{
    int i = blockIdx.x * blockDim.x + threadIdx.x;
    if (i < NB * DH) {
        float c = (float)gcnt[i >> 7];
        out[i] = pool[i] / fmaxf(c, 1.0f);
    }
}

// ---------------- launch ----------------
extern "C" void kernel_launch(void* const* d_in, const int* in_sizes, int n_in,
                              void* d_out, int out_size, void* d_ws, size_t ws_size,
                              hipStream_t stream)
{
    const float* nf    = (const float*)d_in[0];
    const int*   esrc  = (const int*)d_in[1];
    const int*   edst  = esrc + N_EDGES;
    const float* ew    = (const float*)d_in[2];
    const int*   batch = (const int*)d_in[3];
    const float* Wp    = (const float*)d_in[4];
    const float* bp    = (const float*)d_in[5];
    const float* Wl[2]  = {(const float*)d_in[6],  (const float*)d_in[14]};
    const float* asl[2] = {(const float*)d_in[7],  (const float*)d_in[15]};
    const float* adl[2] = {(const float*)d_in[8],  (const float*)d_in[16]};
    const float* Wel[2] = {(const float*)d_in[9],  (const float*)d_in[17]};
    const float* ael[2] = {(const float*)d_in[10], (const float*)d_in[18]};
    const float* bl[2]  = {(const float*)d_in[11], (const float*)d_in[19]};
    const float* gl[2]  = {(const float*)d_in[12], (const float*)d_in[20]};
    const float* bel[2] = {(const float*)d_in[13], (const float*)d_in[21]};
    float* outp = (float*)d_out;

    char* w = (char*)d_ws;
    auto alloc = [&](size_t bytes) { char* p = w; w += (bytes + 255) & ~255ull; return p; };
    float* xA     = (float*)alloc((size_t)N_NODES * DH * 4);
    float* xB     = (float*)alloc((size_t)N_NODES * DH * 4);
    unsigned short* hbuf = (unsigned short*)alloc((size_t)N_NODES * DH * 2);
    float* asrc   = (float*)alloc((size_t)N_NODES * 4 * 4);
    float* adst   = (float*)alloc((size_t)N_NODES * 4 * 4);
    // contiguous zero-init group: pool | gcnt | ews | cnt  (one memset)
    float* pool   = (float*)alloc((size_t)NB * DH * 4);     // 32768 B
    int* gcnt     = (int*)alloc(256);
    float* ews    = (float*)alloc(256);
    int* cnt      = (int*)alloc((size_t)N_NODES * 4);
    int* scanned  = (int*)alloc((size_t)N_NODES * 4);
    int* bsums    = (int*)alloc(1024);
    int* ptr      = (int*)alloc((size_t)(N_NODES + 8) * 4);
    int* rank     = (int*)alloc((size_t)N_EDGES * 4);
    int* srcQ     = (int*)alloc((size_t)N_EDGES * 4);
    int4* recQ    = (int4*)alloc((size_t)N_EDGES * 16);
    float* alQ    = (float*)alloc((size_t)N_EDGES * 4 * 4);

    hipMemsetAsync(pool, 0, (size_t)NB * DH * 4 + 256 + 256 + (size_t)N_NODES * 4, stream);

    const int eb = (N_EDGES + 255) / 256;  // 3125
    const int sb = (N_NODES + 255) / 256;  // 196

    histew_kernel<<<1024, 256, 0, stream>>>(edst, ew, cnt, rank, ews);
    scan_a<<<sb, 256, 0, stream>>>(cnt, scanned, bsums);
    scan_b<<<1, 256, 0, stream>>>(bsums, sb);
    scan_c<<<sb, 256, 0, stream>>>(scanned, bsums, cnt, ptr);
    fill_kernel<<<(N_EDGES / 4 + 255) / 256, 256, 0, stream>>>(esrc, edst, ew, rank, ptr, recQ);

    const int gb = (N_NODES + 63) / 64;  // 782
    mfma_gemm<DIN, false><<<gb, 256, 0, stream>>>(nf, Wp, bp, xA, N_NODES,
                                                  nullptr, nullptr, nullptr, nullptr);

    const float* xin = xA;
    float* xout = xB;
    for (int l = 0; l < 2; ++l) {
        mfma_gemm<DH, true><<<gb, 256, 0, stream>>>(xin, Wl[l], nullptr, hbuf, N_NODES,
                                                    asl[l], adl[l], asrc, adst);
        alpha_kernel<<<eb, 256, 0, stream>>>(recQ, asrc, adst, Wel[l], ael[l], alQ, srcQ);
        msg_kernel<<<(N_NODES + MSG_NPB - 1) / MSG_NPB, 256, 0, stream>>>(
            hbuf, asrc, adst, xin, ptr, srcQ, alQ, ews,
            Wel[l], ael[l], bl[l], gl[l], bel[l], xout);
        float* tmp = (float*)xin; xin = xout; xout = tmp;
    }

    pool_kernel<<<(N_NODES + PNODES - 1) / PNODES, 128, 0, stream>>>(xin, batch, pool, gcnt);
    div_kernel<<<(NB * DH + 255) / 256, 256, 0, stream>>>(pool, gcnt, outp);
}